// Round 6
// baseline (202.447 us; speedup 1.0000x reference)
//
#include <hip/hip_runtime.h>

// Trilinear feature-grid interpolation, LDS-staged spatial bins v2.
// grid layout: [R][R][R][3] = [z][y][x][c], R=256, fp32 (192 MB).
//
// Round-5 evidence: k_gather is staging-BW bound (241 MB of scattered 204B
// chunks from HBM at ~2 TB/s). v2: bins are 64x8x8 cells -> slab chunks are
// 780B contiguous (13 sequential lines) for HBM burst efficiency. Scatter is
// two-level (coarse 64 bins -> local fine sort) so all payload writes are
// 256B-aggregated instead of 16B-random.

#define NB_F   4096
#define NB_C   64
#define GBLK   512
#define CHUNKF 196                 // padded floats per x-chunk (195 used)
#define NCHUNK 81                  // 9 z-rows x 9 y-rows
#define LDSF   (NCHUNK * CHUNKF)   // 15876 floats = 63504 B

// ws layout
#define OFF_FINE_OFF  0u           // u32[4097]
#define C_OFF_OFF     16640u       // u32[65]
#define C_CUR_OFF     17152u       // u32[64]
#define C_HIST_OFF    17664u       // u32[64]
#define F_CUR_OFF     18176u       // u32[4096]
#define F_HIST_OFF    34560u       // u32[4096]
#define BINA_OFF      131072u      // float4[2^21] = 32 MB
#define BINB_OFF      (131072u + 33554432u)
#define NEEDED1 (131072u + 33554432u)               // single-phase scatter
#define NEEDED2 (131072u + 67108864u)               // two-phase scatter

typedef float f4v __attribute__((ext_vector_type(4)));
typedef float f2v __attribute__((ext_vector_type(2)));
typedef f4v f4u __attribute__((aligned(8)));
typedef f2v f2u __attribute__((aligned(8)));

__device__ __forceinline__ void cell_of(float p, int& l, float& t) {
    float s = p * 255.0f;
    int v = (int)floorf(s);
    v = v < 0 ? 0 : (v > 254 ? 254 : v);
    l = v;
    t = s - (float)v;
}

// fine bin: xb = xl>>6 (4), yb = yl>>3 (32), zb = zl>>3 (32)
__device__ __forceinline__ int fine_bin(float px, float py, float pz) {
    int xl, yl, zl; float tx, ty, tz;
    cell_of(px, xl, tx);
    cell_of(py, yl, ty);
    cell_of(pz, zl, tz);
    return ((((zl >> 3) << 5) | (yl >> 3)) << 2) | (xl >> 6);
}

// ================= two-phase scatter path =================

__global__ __launch_bounds__(1024) void k_hist_c(const float* __restrict__ inp,
                                                 unsigned* __restrict__ hist, int n) {
    __shared__ unsigned h[NB_C];
    int t = threadIdx.x;
    if (t < NB_C) h[t] = 0;
    __syncthreads();
    int stride = gridDim.x * 1024;
    for (int i = blockIdx.x * 1024 + t; i < n; i += stride) {
        int c = fine_bin(inp[3 * i], inp[3 * i + 1], inp[3 * i + 2]) >> 6;
        atomicAdd(&h[c], 1u);
    }
    __syncthreads();
    if (t < NB_C && h[t]) atomicAdd(&hist[t], h[t]);
}

__global__ __launch_bounds__(64) void k_scan_c(const unsigned* __restrict__ hist,
                                               unsigned* __restrict__ c_off,
                                               unsigned* __restrict__ c_cur) {
    __shared__ unsigned s[NB_C];
    int t = threadIdx.x;
    unsigned v = hist[t];
    s[t] = v;
    __syncthreads();
    for (int d = 1; d < NB_C; d <<= 1) {
        unsigned add = (t >= d) ? s[t - d] : 0u;
        __syncthreads();
        s[t] += add;
        __syncthreads();
    }
    c_off[t] = s[t] - v;
    c_cur[t] = s[t] - v;
    if (t == NB_C - 1) c_off[NB_C] = s[NB_C - 1];
}

__global__ __launch_bounds__(1024) void k_scatter_c(const float* __restrict__ inp,
                                                    float4* __restrict__ binA,
                                                    unsigned* __restrict__ c_cur, int n) {
    __shared__ unsigned cnt[NB_C];
    __shared__ unsigned base[NB_C];
    int t = threadIdx.x;
    int stride = gridDim.x * 1024;
    int iters = (n + stride - 1) / stride;
    for (int it = 0; it < iters; ++it) {
        int i = it * stride + blockIdx.x * 1024 + t;
        if (t < NB_C) cnt[t] = 0;
        __syncthreads();
        int c = 0; unsigned r = 0; float px = 0, py = 0, pz = 0;
        bool valid = (i < n);
        if (valid) {
            px = inp[3 * i];
            py = inp[3 * i + 1];
            pz = inp[3 * i + 2];
            c = fine_bin(px, py, pz) >> 6;
            r = atomicAdd(&cnt[c], 1u);
        }
        __syncthreads();
        if (t < NB_C && cnt[t]) base[t] = atomicAdd(&c_cur[t], cnt[t]);
        __syncthreads();
        if (valid) {
            float4 v;
            v.x = px; v.y = py; v.z = pz; v.w = __uint_as_float((unsigned)i);
            binA[base[c] + r] = v;
        }
        __syncthreads();
    }
}

// one block per coarse bin: local fine sort (binA -> binB), emit fine offsets
__global__ __launch_bounds__(1024) void k_scatter_f(const float4* __restrict__ binA,
                                                    float4* __restrict__ binB,
                                                    const unsigned* __restrict__ c_off,
                                                    unsigned* __restrict__ off_fine) {
    __shared__ unsigned h[NB_C];
    __shared__ unsigned cur[NB_C];
    int t = threadIdx.x;
    int c = blockIdx.x;
    unsigned s0 = c_off[c], s1 = c_off[c + 1];
    if (t < NB_C) h[t] = 0;
    __syncthreads();
    for (unsigned p = s0 + (unsigned)t; p < s1; p += 1024u) {
        float4 v = binA[p];
        int l = fine_bin(v.x, v.y, v.z) & 63;
        atomicAdd(&h[l], 1u);
    }
    __syncthreads();
    if (t == 0) {
        unsigned run = s0;
        for (int k = 0; k < NB_C; ++k) {
            cur[k] = run;
            run += h[k];
        }
    }
    __syncthreads();
    if (t < NB_C) off_fine[c * NB_C + t] = cur[t];
    if (c == NB_C - 1 && t == 0) off_fine[NB_F] = c_off[NB_C];
    __syncthreads();
    for (unsigned p = s0 + (unsigned)t; p < s1; p += 1024u) {
        float4 v = binA[p];
        int l = fine_bin(v.x, v.y, v.z) & 63;
        unsigned r = atomicAdd(&cur[l], 1u);
        binB[r] = v;
    }
}

// ================= single-phase scatter fallback =================

__global__ __launch_bounds__(1024) void k_hist_f(const float* __restrict__ inp,
                                                 unsigned* __restrict__ hist, int n) {
    __shared__ unsigned h[NB_F];
    int t = threadIdx.x;
    for (int i = t; i < NB_F; i += 1024) h[i] = 0;
    __syncthreads();
    int stride = gridDim.x * 1024;
    for (int i = blockIdx.x * 1024 + t; i < n; i += stride)
        atomicAdd(&h[fine_bin(inp[3 * i], inp[3 * i + 1], inp[3 * i + 2])], 1u);
    __syncthreads();
    for (int i = t; i < NB_F; i += 1024)
        if (h[i]) atomicAdd(&hist[i], h[i]);
}

__global__ __launch_bounds__(1024) void k_scan_f(const unsigned* __restrict__ hist,
                                                 unsigned* __restrict__ off,
                                                 unsigned* __restrict__ cur) {
    __shared__ unsigned s[1024];
    int t = threadIdx.x;
    unsigned v0 = hist[4 * t], v1 = hist[4 * t + 1];
    unsigned v2 = hist[4 * t + 2], v3 = hist[4 * t + 3];
    unsigned sum = v0 + v1 + v2 + v3;
    s[t] = sum;
    __syncthreads();
    for (int d = 1; d < 1024; d <<= 1) {
        unsigned add = (t >= d) ? s[t - d] : 0u;
        __syncthreads();
        s[t] += add;
        __syncthreads();
    }
    unsigned excl = s[t] - sum;
    unsigned e0 = excl, e1 = excl + v0, e2 = e1 + v1, e3 = e2 + v2;
    off[4 * t] = e0;     cur[4 * t] = e0;
    off[4 * t + 1] = e1; cur[4 * t + 1] = e1;
    off[4 * t + 2] = e2; cur[4 * t + 2] = e2;
    off[4 * t + 3] = e3; cur[4 * t + 3] = e3;
    if (t == 1023) off[NB_F] = s[1023];
}

__global__ __launch_bounds__(1024) void k_scatter_1(const float* __restrict__ inp,
                                                    float4* __restrict__ binA,
                                                    unsigned* __restrict__ cur, int n) {
    __shared__ unsigned cnt[NB_F];
    __shared__ unsigned base[NB_F];
    int t = threadIdx.x;
    int stride = gridDim.x * 1024;
    int iters = (n + stride - 1) / stride;
    for (int it = 0; it < iters; ++it) {
        int i = it * stride + blockIdx.x * 1024 + t;
        for (int k = t; k < NB_F; k += 1024) cnt[k] = 0;
        __syncthreads();
        int b = 0; unsigned r = 0; float px = 0, py = 0, pz = 0;
        bool valid = (i < n);
        if (valid) {
            px = inp[3 * i];
            py = inp[3 * i + 1];
            pz = inp[3 * i + 2];
            b = fine_bin(px, py, pz);
            r = atomicAdd(&cnt[b], 1u);
        }
        __syncthreads();
        for (int k = t; k < NB_F; k += 1024)
            if (cnt[k]) base[k] = atomicAdd(&cur[k], cnt[k]);
        __syncthreads();
        if (valid) {
            float4 v;
            v.x = px; v.y = py; v.z = pz; v.w = __uint_as_float((unsigned)i);
            binA[base[b] + r] = v;
        }
        __syncthreads();
    }
}

// ================= LDS-staged gather / trilerp =================
__global__ __launch_bounds__(GBLK) void k_gather(const float4* __restrict__ binned,
                                                 const float* __restrict__ grid,
                                                 const unsigned* __restrict__ off,
                                                 float* __restrict__ out) {
    __shared__ float slab[LDSF];
    int bin = blockIdx.x;
    int x0 = (bin & 3) << 6;          // 0,64,128,192
    int y0 = ((bin >> 2) & 31) << 3;  // 0..248
    int z0 = (bin >> 7) << 3;         // 0..248
    int t = threadIdx.x;

    // Stage 81 chunks of 65 cells (195 floats, 780B contiguous; load 196
    // floats = 49 float4; skip the last load at x0=192 to stay in bounds —
    // those floats are select-discarded garbage anyway).
    for (int u = t; u < NCHUNK * 49; u += GBLK) {
        int chunk = u / 49;
        int j = u - chunk * 49;
        if (j == 48 && x0 == 192) continue;
        int zc = chunk / 9;
        int yc = chunk - zc * 9;
        int zg = z0 + zc; zg = zg > 255 ? 255 : zg;   // clamped rows unread
        int yg = y0 + yc; yg = yg > 255 ? 255 : yg;
        const float* src = grid + (size_t)((zg << 16) | (yg << 8) | x0) * 3 + (j << 2);
        *(f4v*)(&slab[chunk * CHUNKF + (j << 2)]) = *(const f4u*)src;
    }
    __syncthreads();

    unsigned start = off[bin], end = off[bin + 1];
    for (unsigned p = start + (unsigned)t; p < end; p += (unsigned)GBLK) {
        float4 v = binned[p];
        int xl, yl, zl; float tx, ty, tz;
        cell_of(v.x, xl, tx);
        cell_of(v.y, yl, ty);
        cell_of(v.z, zl, tz);
        int xc = xl - x0, yc = yl - y0, zc = zl - z0;

        int r0 = (zc * 9 + yc) * CHUNKF + xc * 3;
        int e = r0 & ~1;
        bool d = (r0 & 1) != 0;

#define SEG_READ(b, s)                                   \
        do {                                             \
            f2v q0 = *(const f2u*)(&slab[(b)]);          \
            f2v q1 = *(const f2u*)(&slab[(b) + 2]);      \
            f2v q2 = *(const f2u*)(&slab[(b) + 4]);      \
            f2v q3 = *(const f2u*)(&slab[(b) + 6]);      \
            s[0] = d ? q0.y : q0.x;                      \
            s[1] = d ? q1.x : q0.y;                      \
            s[2] = d ? q1.y : q1.x;                      \
            s[3] = d ? q2.x : q1.y;                      \
            s[4] = d ? q2.y : q2.x;                      \
            s[5] = d ? q3.x : q2.y;                      \
        } while (0)

        float s00[6], s01[6], s10[6], s11[6];
        SEG_READ(e,                s00);   // (zc,   yc)
        SEG_READ(e + CHUNKF,       s01);   // (zc,   yc+1)
        SEG_READ(e + 9 * CHUNKF,   s10);   // (zc+1, yc)
        SEG_READ(e + 10 * CHUNKF,  s11);   // (zc+1, yc+1)
#undef SEG_READ

        unsigned idx = __float_as_uint(v.w);
        float* o = out + 3 * (int)idx;
#pragma unroll
        for (int c = 0; c < 3; ++c) {
            float c00 = s00[c] * (1.0f - tx) + s00[c + 3] * tx;
            float c01 = s01[c] * (1.0f - tx) + s01[c + 3] * tx;
            float c10 = s10[c] * (1.0f - tx) + s10[c + 3] * tx;
            float c11 = s11[c] * (1.0f - tx) + s11[c + 3] * tx;
            float c0 = c00 * (1.0f - ty) + c01 * ty;
            float c1 = c10 * (1.0f - ty) + c11 * ty;
            o[c] = c0 * (1.0f - tz) + c1 * tz;
        }
    }
}

// ================= fallback: direct =================
__global__ __launch_bounds__(256) void k_direct(const float* __restrict__ inp,
                                                const float* __restrict__ grid,
                                                float* __restrict__ out, int n) {
    int i = blockIdx.x * blockDim.x + threadIdx.x;
    if (i >= n) return;
    int xl, yl, zl; float tx, ty, tz;
    cell_of(inp[3 * i + 0], xl, tx);
    cell_of(inp[3 * i + 1], yl, ty);
    cell_of(inp[3 * i + 2], zl, tz);
    int b00 = (zl * 65536 + yl * 256 + xl) * 3;
    int b01 = b00 + 768, b10 = b00 + 196608, b11 = b10 + 768;
    float s00[6], s01[6], s10[6], s11[6];
#pragma unroll
    for (int kk = 0; kk < 6; ++kk) s00[kk] = grid[b00 + kk];
#pragma unroll
    for (int kk = 0; kk < 6; ++kk) s01[kk] = grid[b01 + kk];
#pragma unroll
    for (int kk = 0; kk < 6; ++kk) s10[kk] = grid[b10 + kk];
#pragma unroll
    for (int kk = 0; kk < 6; ++kk) s11[kk] = grid[b11 + kk];
#pragma unroll
    for (int c = 0; c < 3; ++c) {
        float c00 = s00[c] * (1.0f - tx) + s00[c + 3] * tx;
        float c01 = s01[c] * (1.0f - tx) + s01[c + 3] * tx;
        float c10 = s10[c] * (1.0f - tx) + s10[c + 3] * tx;
        float c11 = s11[c] * (1.0f - tx) + s11[c + 3] * tx;
        float c0 = c00 * (1.0f - ty) + c01 * ty;
        float c1 = c10 * (1.0f - ty) + c11 * ty;
        out[3 * i + c] = c0 * (1.0f - tz) + c1 * tz;
    }
}

extern "C" void kernel_launch(void* const* d_in, const int* in_sizes, int n_in,
                              void* d_out, int out_size, void* d_ws, size_t ws_size,
                              hipStream_t stream) {
    const float* inp  = (const float*)d_in[0];  // [N][3]
    const float* grid = (const float*)d_in[1];  // [256][256][256][3]
    float* out = (float*)d_out;                 // [N][3]
    int n = in_sizes[0] / 3;

    if (ws_size < (size_t)NEEDED1) {
        int blocks = (n + 255) / 256;
        k_direct<<<blocks, 256, 0, stream>>>(inp, grid, out, n);
        return;
    }

    char* ws = (char*)d_ws;
    unsigned* off_fine = (unsigned*)(ws + OFF_FINE_OFF);
    unsigned* c_off    = (unsigned*)(ws + C_OFF_OFF);
    unsigned* c_cur    = (unsigned*)(ws + C_CUR_OFF);
    unsigned* c_hist   = (unsigned*)(ws + C_HIST_OFF);
    unsigned* f_cur    = (unsigned*)(ws + F_CUR_OFF);
    unsigned* f_hist   = (unsigned*)(ws + F_HIST_OFF);
    float4*   binA     = (float4*)(ws + BINA_OFF);
    float4*   binB     = (float4*)(ws + BINB_OFF);

    if (ws_size >= (size_t)NEEDED2) {
        // two-phase scatter: coarse (aggregated) then local fine sort
        hipMemsetAsync(c_hist, 0, NB_C * sizeof(unsigned), stream);
        k_hist_c   <<<256, 1024, 0, stream>>>(inp, c_hist, n);
        k_scan_c   <<<1,   NB_C, 0, stream>>>(c_hist, c_off, c_cur);
        k_scatter_c<<<256, 1024, 0, stream>>>(inp, binA, c_cur, n);
        k_scatter_f<<<NB_C, 1024, 0, stream>>>(binA, binB, c_off, off_fine);
        k_gather   <<<NB_F, GBLK, 0, stream>>>(binB, grid, off_fine, out);
    } else {
        // single-phase scatter fallback
        hipMemsetAsync(f_hist, 0, NB_F * sizeof(unsigned), stream);
        k_hist_f   <<<256, 1024, 0, stream>>>(inp, f_hist, n);
        k_scan_f   <<<1,   1024, 0, stream>>>(f_hist, off_fine, f_cur);
        k_scatter_1<<<256, 1024, 0, stream>>>(inp, binA, f_cur, n);
        k_gather   <<<NB_F, GBLK, 0, stream>>>(binA, grid, off_fine, out);
    }
}